// Round 4
// baseline (699.440 us; speedup 1.0000x reference)
//
#include <hip/hip_runtime.h>
#include <hip/hip_fp16.h>

typedef __attribute__((ext_vector_type(8))) short bf16x8;
typedef __attribute__((ext_vector_type(4))) float f32x4;

__device__ __forceinline__ f32x4 mfma16(bf16x8 a, bf16x8 b, f32x4 c) {
    return __builtin_amdgcn_mfma_f32_16x16x32_bf16(a, b, c, 0, 0, 0);
}

__device__ __forceinline__ unsigned short bf16_rte(float f) {
    unsigned int u = __float_as_uint(f);
    unsigned int r = (u + 0x7FFFu + ((u >> 16) & 1u)) >> 16;
    return (unsigned short)r;
}
__device__ __forceinline__ float bf16_f(unsigned short h) {
    return __uint_as_float(((unsigned int)h) << 16);
}

// split 8 fp16 values (bit-packed) into bf16 hi/lo (exact: fp16 has 11 mantissa
// bits, hi captures 8, lo captures the rest)
__device__ __forceinline__ void split8h(bf16x8 raw, bf16x8& hi, bf16x8& lo) {
#pragma unroll
    for (int j = 0; j < 8; ++j) {
        float f = __half2float(__ushort_as_half((unsigned short)raw[j]));
        unsigned short h = bf16_rte(f);
        hi[j] = (short)h;
        lo[j] = (short)bf16_rte(f - bf16_f(h));
    }
}

// ---------------- weight pre-conversion to fragment layout ----------------
__global__ void k_wconv(const float* __restrict__ W, unsigned short* __restrict__ hi,
                        unsigned short* __restrict__ lo, int K, int F) {
    int e = blockIdx.x * 256 + threadIdx.x;
    if (e >= K * F) return;
    int col = e / K, k = e - col * K;
    float v = W[(size_t)k * F + col];
    unsigned short h = bf16_rte(v);
    hi[e] = h;
    lo[e] = bf16_rte(v - bf16_f(h));
}

// ---------------- x fp32 -> SLICED fp16 gather table ----------------
// xs[s][node][16] halfs: 32 B per row-slice; one 3.2 MB slice per XCD L2.
__global__ __launch_bounds__(256) void k_xslice(const float* __restrict__ x,
                                                unsigned short* __restrict__ xs,
                                                int n) {
    int t = blockIdx.x * 256 + threadIdx.x;
    int node = t >> 3, s = t & 7;
    if (node >= n) return;
    const float4* p = (const float4*)(x + (size_t)node * 128 + s * 16);
    float4 v0 = p[0], v1 = p[1], v2 = p[2], v3 = p[3];
    bf16x8 o0, o1;
    o0[0] = (short)__half_as_ushort(__float2half_rn(v0.x));
    o0[1] = (short)__half_as_ushort(__float2half_rn(v0.y));
    o0[2] = (short)__half_as_ushort(__float2half_rn(v0.z));
    o0[3] = (short)__half_as_ushort(__float2half_rn(v0.w));
    o0[4] = (short)__half_as_ushort(__float2half_rn(v1.x));
    o0[5] = (short)__half_as_ushort(__float2half_rn(v1.y));
    o0[6] = (short)__half_as_ushort(__float2half_rn(v1.z));
    o0[7] = (short)__half_as_ushort(__float2half_rn(v1.w));
    o1[0] = (short)__half_as_ushort(__float2half_rn(v2.x));
    o1[1] = (short)__half_as_ushort(__float2half_rn(v2.y));
    o1[2] = (short)__half_as_ushort(__float2half_rn(v2.z));
    o1[3] = (short)__half_as_ushort(__float2half_rn(v2.w));
    o1[4] = (short)__half_as_ushort(__float2half_rn(v3.x));
    o1[5] = (short)__half_as_ushort(__float2half_rn(v3.y));
    o1[6] = (short)__half_as_ushort(__float2half_rn(v3.z));
    o1[7] = (short)__half_as_ushort(__float2half_rn(v3.w));
    unsigned short* dp = xs + ((size_t)s * n + node) * 16;
    *(bf16x8*)dp = o0;
    *(bf16x8*)(dp + 8) = o1;
}

// ---------------- bucketed CSR build, two-level (proven) ------------

#define MAXNB 1024

__global__ __launch_bounds__(256) void k_bcount(
    const int* __restrict__ dst, int* __restrict__ bcnt, int E, int chunk, int nb) {
    __shared__ int h[MAXNB];
    int t = threadIdx.x;
    for (int i = t; i < nb; i += 256) h[i] = 0;
    __syncthreads();
    int base = blockIdx.x * chunk;
    int end = min(base + chunk, E);
    for (int i = base + t; i < end; i += 256) atomicAdd(&h[dst[i] >> 7], 1);
    __syncthreads();
    for (int i = t; i < nb; i += 256)
        if (h[i]) atomicAdd(&bcnt[i], h[i]);
}

__global__ void k_bscan(const int* __restrict__ bcnt, int* __restrict__ boff,
                        int* __restrict__ bcur, int nb) {
    __shared__ int sh[1024];
    int t = threadIdx.x;
    int v = (t < nb) ? bcnt[t] : 0;
    sh[t] = v;
    __syncthreads();
    for (int off = 1; off < 1024; off <<= 1) {
        int u = (t >= off) ? sh[t - off] : 0;
        __syncthreads();
        sh[t] += u;
        __syncthreads();
    }
    if (t < nb) {
        int ex = sh[t] - v;
        boff[t] = ex;
        bcur[t] = ex;
    }
}

__global__ __launch_bounds__(256) void k_bscatter(
    const int* __restrict__ src, const int* __restrict__ dst,
    int* __restrict__ bcur, int2* __restrict__ pairs, int E, int chunk, int nb) {
    __shared__ int h[MAXNB];
    __shared__ int curs[MAXNB];
    int t = threadIdx.x;
    for (int i = t; i < nb; i += 256) h[i] = 0;
    __syncthreads();
    int base = blockIdx.x * chunk;
    int end = min(base + chunk, E);
    for (int i = base + t; i < end; i += 256) atomicAdd(&h[dst[i] >> 7], 1);
    __syncthreads();
    for (int i = t; i < nb; i += 256)
        curs[i] = h[i] ? atomicAdd(&bcur[i], h[i]) : 0;
    __syncthreads();
    for (int i = base + t; i < end; i += 256) {
        int d = dst[i];
        int p = atomicAdd(&curs[d >> 7], 1);
        pairs[p] = make_int2(d, src[i]);
    }
}

__global__ __launch_bounds__(256) void k_build(
    const int2* __restrict__ pairs, const int* __restrict__ boff,
    int* __restrict__ csr, int* __restrict__ start, int* __restrict__ deg,
    int n, int nb, int E) {
    __shared__ int scnt[128];
    __shared__ int soff[128];
    __shared__ int cur[128];
    int b = blockIdx.x;
    int t = threadIdx.x;
    int base = boff[b];
    int end = (b + 1 < nb) ? boff[b + 1] : E;
    if (t < 128) scnt[t] = 0;
    __syncthreads();
    for (int i = base + t; i < end; i += 256) {
        int2 e = pairs[i];
        atomicAdd(&scnt[e.x & 127], 1);
    }
    __syncthreads();
    if (t < 128) soff[t] = scnt[t];
    __syncthreads();
    for (int off = 1; off < 128; off <<= 1) {
        int val = 0;
        if (t < 128 && t >= off) val = soff[t - off];
        __syncthreads();
        if (t < 128) soff[t] += val;
        __syncthreads();
    }
    if (t < 128) {
        int c = scnt[t];
        int ex = soff[t] - c;
        int node = b * 128 + t;
        if (node < n) {
            start[node] = base + ex;
            deg[node] = c;
        }
        cur[t] = base + ex;
    }
    __syncthreads();
    for (int i = base + t; i < end; i += 256) {
        int2 e = pairs[i];
        int p = atomicAdd(&cur[e.x & 127], 1);
        csr[p] = e.y;
    }
}

// ---------------- dual-source fused GEMM (round-3 core, proven) ----------------
// acc = X0@W0 + X1@W1 per 64-node tile, two LDS phases, 4 waves over cols.
// OUT_H16 epilogue now ALSO emits the sliced gather table for aggS.

#define SR 40

template <int FOUT, bool S0F32, bool OUT_H16>
__device__ __forceinline__ void gemm_dual_body(
    const float* __restrict__ X0f, const unsigned short* __restrict__ X0h,
    const unsigned short* __restrict__ X1h,
    const unsigned short* __restrict__ W0H, const unsigned short* __restrict__ W0L,
    const unsigned short* __restrict__ W1H, const unsigned short* __restrict__ W1L,
    const float* __restrict__ bias, unsigned short* __restrict__ dstH,
    unsigned short* __restrict__ dstS, float* __restrict__ dstF, int n) {
    constexpr int CT = FOUT / 64;  // 16-col tiles per wave (4 waves cover FOUT)
    __shared__ unsigned short aHi[4][64 * SR], aLo[4][64 * SR];

    int t = threadIdx.x;
    int wv = t >> 6, l = t & 63, q = l >> 4, nl = l & 15;
    int wc = wv * (FOUT / 4);
    int node0 = blockIdx.x * 64;
    int sn = t >> 2, q4 = t & 3;  // staging: 4 threads per node
    int gn = min(node0 + sn, n - 1);

    // S1 row prefetch into regs (fp16)
    bf16x8 s1r[4];
    {
        const unsigned short* p = X1h + (size_t)gn * 128 + q4 * 8;
#pragma unroll
        for (int c = 0; c < 4; ++c) s1r[c] = *(const bf16x8*)(p + c * 32);
    }
    // W1 chunk-0 frag preload
    bf16x8 w1h0[CT], w1l0[CT];
#pragma unroll
    for (int uu = 0; uu < CT; ++uu) {
        int base = (wc + uu * 16 + nl) * 128 + q * 8;
        w1h0[uu] = *(const bf16x8*)&W1H[base];
        w1l0[uu] = *(const bf16x8*)&W1L[base];
    }

    // ---- phase 0: stage S0 (all of K=128), 1 barrier, 4-chunk MFMA ----
    if (S0F32) {
        const float4* ap = (const float4*)(X0f + (size_t)gn * 128);
        float4 xa[8];
#pragma unroll
        for (int c = 0; c < 4; ++c) {
            xa[c * 2]     = ap[c * 8 + q4 * 2];
            xa[c * 2 + 1] = ap[c * 8 + q4 * 2 + 1];
        }
        int base = sn * SR + q4 * 8;
#pragma unroll
        for (int c = 0; c < 4; ++c) {
            ushort4 hi, lo;
            float4 v = xa[c * 2];
            hi.x = bf16_rte(v.x); lo.x = bf16_rte(v.x - bf16_f(hi.x));
            hi.y = bf16_rte(v.y); lo.y = bf16_rte(v.y - bf16_f(hi.y));
            hi.z = bf16_rte(v.z); lo.z = bf16_rte(v.z - bf16_f(hi.z));
            hi.w = bf16_rte(v.w); lo.w = bf16_rte(v.w - bf16_f(hi.w));
            *(ushort4*)&aHi[c][base] = hi;
            *(ushort4*)&aLo[c][base] = lo;
            v = xa[c * 2 + 1];
            hi.x = bf16_rte(v.x); lo.x = bf16_rte(v.x - bf16_f(hi.x));
            hi.y = bf16_rte(v.y); lo.y = bf16_rte(v.y - bf16_f(hi.y));
            hi.z = bf16_rte(v.z); lo.z = bf16_rte(v.z - bf16_f(hi.z));
            hi.w = bf16_rte(v.w); lo.w = bf16_rte(v.w - bf16_f(hi.w));
            *(ushort4*)&aHi[c][base + 4] = hi;
            *(ushort4*)&aLo[c][base + 4] = lo;
        }
    } else {
        const unsigned short* p = X0h + (size_t)gn * 128 + q4 * 8;
        bf16x8 r[4];
#pragma unroll
        for (int c = 0; c < 4; ++c) r[c] = *(const bf16x8*)(p + c * 32);
        int base = sn * SR + q4 * 8;
#pragma unroll
        for (int c = 0; c < 4; ++c) {
            bf16x8 hi, lo;
            split8h(r[c], hi, lo);
            *(bf16x8*)&aHi[c][base] = hi;
            *(bf16x8*)&aLo[c][base] = lo;
        }
    }

    f32x4 acc[4][CT];
#pragma unroll
    for (int a = 0; a < 4; ++a)
#pragma unroll
        for (int b = 0; b < CT; ++b) acc[a][b] = (f32x4){0.f, 0.f, 0.f, 0.f};

    bf16x8 wh[2][CT], wl[2][CT];
#pragma unroll
    for (int uu = 0; uu < CT; ++uu) {
        int base = (wc + uu * 16 + nl) * 128 + q * 8;
        wh[0][uu] = *(const bf16x8*)&W0H[base];
        wl[0][uu] = *(const bf16x8*)&W0L[base];
    }
    __syncthreads();

#pragma unroll
    for (int c = 0; c < 4; ++c) {
        if (c < 3) {
#pragma unroll
            for (int uu = 0; uu < CT; ++uu) {
                int base = (wc + uu * 16 + nl) * 128 + (c + 1) * 32 + q * 8;
                wh[(c + 1) & 1][uu] = *(const bf16x8*)&W0H[base];
                wl[(c + 1) & 1][uu] = *(const bf16x8*)&W0L[base];
            }
        }
        bf16x8 ah[4], al[4];
#pragma unroll
        for (int tt = 0; tt < 4; ++tt) {
            int off = (tt * 16 + nl) * SR + q * 8;
            ah[tt] = *(const bf16x8*)&aHi[c][off];
            al[tt] = *(const bf16x8*)&aLo[c][off];
        }
        int cb = c & 1;
#pragma unroll
        for (int tt = 0; tt < 4; ++tt)
#pragma unroll
            for (int uu = 0; uu < CT; ++uu) {
                f32x4 a = acc[tt][uu];
                a = mfma16(al[tt], wh[cb][uu], a);
                a = mfma16(ah[tt], wl[cb][uu], a);
                a = mfma16(ah[tt], wh[cb][uu], a);
                acc[tt][uu] = a;
            }
    }
    __syncthreads();

    // ---- phase 1: stage S1 from regs ----
    {
        int base = sn * SR + q4 * 8;
#pragma unroll
        for (int c = 0; c < 4; ++c) {
            bf16x8 hi, lo;
            split8h(s1r[c], hi, lo);
            *(bf16x8*)&aHi[c][base] = hi;
            *(bf16x8*)&aLo[c][base] = lo;
        }
    }
#pragma unroll
    for (int uu = 0; uu < CT; ++uu) { wh[0][uu] = w1h0[uu]; wl[0][uu] = w1l0[uu]; }
    __syncthreads();

#pragma unroll
    for (int c = 0; c < 4; ++c) {
        if (c < 3) {
#pragma unroll
            for (int uu = 0; uu < CT; ++uu) {
                int base = (wc + uu * 16 + nl) * 128 + (c + 1) * 32 + q * 8;
                wh[(c + 1) & 1][uu] = *(const bf16x8*)&W1H[base];
                wl[(c + 1) & 1][uu] = *(const bf16x8*)&W1L[base];
            }
        }
        bf16x8 ah[4], al[4];
#pragma unroll
        for (int tt = 0; tt < 4; ++tt) {
            int off = (tt * 16 + nl) * SR + q * 8;
            ah[tt] = *(const bf16x8*)&aHi[c][off];
            al[tt] = *(const bf16x8*)&aLo[c][off];
        }
        int cb = c & 1;
#pragma unroll
        for (int tt = 0; tt < 4; ++tt)
#pragma unroll
            for (int uu = 0; uu < CT; ++uu) {
                f32x4 a = acc[tt][uu];
                a = mfma16(al[tt], wh[cb][uu], a);
                a = mfma16(ah[tt], wl[cb][uu], a);
                a = mfma16(ah[tt], wh[cb][uu], a);
                acc[tt][uu] = a;
            }
    }
    __syncthreads();

    // ---- epilogue: bias (+relu), LDS transpose, coalesced row stores ----
    if (OUT_H16) {
        unsigned short* tb = &aHi[0][0];  // 64 x 136 ushorts = 17408 B (fits)
#pragma unroll
        for (int uu = 0; uu < CT; ++uu) {
            int col = wc + uu * 16 + nl;
            float bv = bias[col];
#pragma unroll
            for (int tt = 0; tt < 4; ++tt)
#pragma unroll
                for (int r = 0; r < 4; ++r) {
                    float vv = fmaxf(acc[tt][uu][r] + bv, 0.f);
                    tb[(tt * 16 + q * 4 + r) * 136 + col] =
                        __half_as_ushort(__float2half_rn(vv));
                }
        }
        __syncthreads();
        int node = node0 + sn;
        if (node < n) {
            const unsigned short* sp = tb + sn * 136 + q4 * 32;
            unsigned short* dp = dstH + (size_t)node * 128 + q4 * 32;
#pragma unroll
            for (int i = 0; i < 4; ++i) *(bf16x8*)(dp + i * 8) = *(const bf16x8*)(sp + i * 8);
            // sliced table: cols [q4*32, q4*32+32) = slices 2*q4, 2*q4+1
            unsigned short* e0 = dstS + ((size_t)(q4 * 2) * n + node) * 16;
            unsigned short* e1 = dstS + ((size_t)(q4 * 2 + 1) * n + node) * 16;
            *(bf16x8*)e0 = *(const bf16x8*)sp;
            *(bf16x8*)(e0 + 8) = *(const bf16x8*)(sp + 8);
            *(bf16x8*)e1 = *(const bf16x8*)(sp + 16);
            *(bf16x8*)(e1 + 8) = *(const bf16x8*)(sp + 24);
        }
    } else {
        float* tb = (float*)&aHi[0][0];  // 64 x 68 floats = 17408 B (fits)
#pragma unroll
        for (int uu = 0; uu < CT; ++uu) {
            int col = wc + uu * 16 + nl;
            float bv = bias[col];
#pragma unroll
            for (int tt = 0; tt < 4; ++tt)
#pragma unroll
                for (int r = 0; r < 4; ++r)
                    tb[(tt * 16 + q * 4 + r) * 68 + col] = acc[tt][uu][r] + bv;
        }
        __syncthreads();
        int node = node0 + sn;
        if (node < n) {
            const float* sp = tb + sn * 68 + q4 * 16;
            float* dp = dstF + (size_t)node * 64 + q4 * 16;
#pragma unroll
            for (int i = 0; i < 4; ++i) *(float4*)(dp + i * 4) = *(const float4*)(sp + i * 4);
        }
    }
}

// layer 1: h16/h16s = relu(x@Wr1 + xm@Wl1 + b1)
__global__ __launch_bounds__(256, 2) void gemm1f(
    const float* __restrict__ X, const unsigned short* __restrict__ XM,
    const unsigned short* WrH, const unsigned short* WrL,
    const unsigned short* WlH, const unsigned short* WlL,
    const float* __restrict__ bias, unsigned short* __restrict__ h16,
    unsigned short* __restrict__ h16s, int n) {
    gemm_dual_body<128, true, true>(X, nullptr, XM, WrH, WrL, WlH, WlL, bias, h16, h16s, nullptr, n);
}

// layer 2: out = h@Wr2 + hm@Wl2 + b2
__global__ __launch_bounds__(256, 2) void gemm2f(
    const unsigned short* __restrict__ H, const unsigned short* __restrict__ HM,
    const unsigned short* WrH, const unsigned short* WrL,
    const unsigned short* WlH, const unsigned short* WlL,
    const float* __restrict__ bias, float* __restrict__ out, int n) {
    gemm_dual_body<64, false, false>(nullptr, H, HM, WrH, WrL, WlH, WlL, bias, nullptr, nullptr, out, n);
}

// ---------------- sliced mean aggregation ----------------
// slice = bid & 7 -> XCD round-robin pins each 3.2 MB slice into one XCD's L2.
// 2 nodes/wave (halves), 8 edge-groups x 4 lanes (8 B/lane of the 32 B row).
// csr/start/deg reads non-temporal so streaming doesn't evict the slice table.
__global__ __launch_bounds__(256) void aggS(
    const unsigned short* __restrict__ tabS, const int* __restrict__ csr,
    const int* __restrict__ start, const int* __restrict__ deg,
    unsigned short* __restrict__ outm, int n) {
    int bid = blockIdx.x;
    int s = bid & 7, chunk = bid >> 3;
    int t = threadIdx.x;
    int wv = t >> 6, l = t & 63;
    int half = l >> 5, eg = (l >> 2) & 7, cq = l & 3;
    const unsigned short* tab = tabS + (size_t)s * n * 16;
    int nbase = chunk * 64 + wv * 16;
#pragma unroll 1
    for (int i = 0; i < 16; i += 2) {
        int node = nbase + i + half;
        if (node < n) {
            int st = __builtin_nontemporal_load(&start[node]);
            int d = __builtin_nontemporal_load(&deg[node]);
            float a0 = 0.f, a1 = 0.f, a2 = 0.f, a3 = 0.f;
            for (int j = eg; j < d; j += 8) {
                int idx = __builtin_nontemporal_load(&csr[st + j]);
                const __half2* p = (const __half2*)(tab + (size_t)idx * 16 + cq * 4);
                float2 u0 = __half22float2(p[0]);
                float2 u1 = __half22float2(p[1]);
                a0 += u0.x; a1 += u0.y; a2 += u1.x; a3 += u1.y;
            }
            // butterfly over the 8 edge-groups (lane bits 2,3,4)
            for (int off = 4; off <= 16; off <<= 1) {
                a0 += __shfl_xor(a0, off);
                a1 += __shfl_xor(a1, off);
                a2 += __shfl_xor(a2, off);
                a3 += __shfl_xor(a3, off);
            }
            if (eg == 0) {
                float inv = 1.f / (float)max(d, 1);
                __half2 h01 = __floats2half2_rn(a0 * inv, a1 * inv);
                __half2 h23 = __floats2half2_rn(a2 * inv, a3 * inv);
                unsigned int* wp = (unsigned int*)&outm[(size_t)node * 128 + s * 16 + cq * 4];
                __builtin_nontemporal_store(*(unsigned int*)&h01, wp);
                __builtin_nontemporal_store(*(unsigned int*)&h23, wp + 1);
            }
        }
    }
}

// ---------------- launch ----------------

extern "C" void kernel_launch(void* const* d_in, const int* in_sizes, int n_in,
                              void* d_out, int out_size, void* d_ws, size_t ws_size,
                              hipStream_t stream) {
    const float* x   = (const float*)d_in[0];
    const int*   ei  = (const int*)d_in[1];
    const float* Wl1 = (const float*)d_in[2];
    const float* Wr1 = (const float*)d_in[3];
    const float* b1  = (const float*)d_in[4];
    const float* Wl2 = (const float*)d_in[5];
    const float* Wr2 = (const float*)d_in[6];
    const float* b2  = (const float*)d_in[7];
    float* out = (float*)d_out;

    int Nn = in_sizes[0] / 128;
    int E  = in_sizes[1] / 2;
    const int* src = ei;
    const int* dst = ei + E;
    int nb = (Nn + 127) / 128;  // 782 <= MAXNB

    char* ws = (char*)d_ws;
    auto alloc = [&](size_t bytes) -> char* {
        char* pp = ws;
        ws += (bytes + 255) / 256 * 256;
        return pp;
    };
    int* bcnt   = (int*)alloc((size_t)nb * 4);
    int* boff   = (int*)alloc((size_t)nb * 4);
    int* bcur   = (int*)alloc((size_t)nb * 4);
    int* start  = (int*)alloc((size_t)Nn * 4);
    int* deg    = (int*)alloc((size_t)Nn * 4);
    int* csr    = (int*)alloc((size_t)E * 4);
    unsigned short* x16s = (unsigned short*)alloc((size_t)Nn * 128 * 2);  // sliced
    unsigned short* xm16 = (unsigned short*)alloc((size_t)Nn * 128 * 2);
    unsigned short* h16  = (unsigned short*)alloc((size_t)Nn * 128 * 2);  // row-major
    unsigned short* h16s = (unsigned short*)alloc((size_t)Nn * 128 * 2);  // sliced
    unsigned short* hm16 = (unsigned short*)alloc((size_t)Nn * 128 * 2);
    unsigned short* w1ah = (unsigned short*)alloc(128 * 128 * 2);
    unsigned short* w1al = (unsigned short*)alloc(128 * 128 * 2);
    unsigned short* w1bh = (unsigned short*)alloc(128 * 128 * 2);
    unsigned short* w1bl = (unsigned short*)alloc(128 * 128 * 2);
    unsigned short* w2ah = (unsigned short*)alloc(64 * 128 * 2);
    unsigned short* w2al = (unsigned short*)alloc(64 * 128 * 2);
    unsigned short* w2bh = (unsigned short*)alloc(64 * 128 * 2);
    unsigned short* w2bl = (unsigned short*)alloc(64 * 128 * 2);
    // pairs (12.8 MB) aliases hm16 (25.6 MB): consumed by k_build before
    // aggS(h16s) writes hm16
    int2* pairs = (int2*)hm16;

    hipMemsetAsync(bcnt, 0, (size_t)nb * 4, stream);

    k_wconv<<<64, 256, 0, stream>>>(Wl1, w1ah, w1al, 128, 128);
    k_wconv<<<64, 256, 0, stream>>>(Wr1, w1bh, w1bl, 128, 128);
    k_wconv<<<32, 256, 0, stream>>>(Wl2, w2ah, w2al, 128, 64);
    k_wconv<<<32, 256, 0, stream>>>(Wr2, w2bh, w2bl, 128, 64);
    k_xslice<<<(Nn * 8 + 255) / 256, 256, 0, stream>>>(x, x16s, Nn);

    int chunk = (E + 255) / 256;
    k_bcount<<<256, 256, 0, stream>>>(dst, bcnt, E, chunk, nb);
    k_bscan<<<1, 1024, 0, stream>>>(bcnt, boff, bcur, nb);
    k_bscatter<<<256, 256, 0, stream>>>(src, dst, bcur, pairs, E, chunk, nb);
    k_build<<<nb, 256, 0, stream>>>(pairs, boff, csr, start, deg, Nn, nb, E);

    int gb = (Nn + 63) / 64;
    int ga = ((Nn + 63) / 64) * 8;  // slice-interleaved grid
    // layer 1: xm = mean-agg(x); h = relu(xm@Wl1 + x@Wr1 + b1)   [linearity]
    aggS<<<ga, 256, 0, stream>>>(x16s, csr, start, deg, xm16, Nn);
    gemm1f<<<gb, 256, 0, stream>>>(x, xm16, w1bh, w1bl, w1ah, w1al, b1, h16, h16s, Nn);
    // layer 2: hm = mean-agg(h); out = hm@Wl2 + h@Wr2 + b2       [linearity]
    aggS<<<ga, 256, 0, stream>>>(h16s, csr, start, deg, hm16, Nn);
    gemm2f<<<gb, 256, 0, stream>>>(h16, hm16, w2bh, w2bl, w2ah, w2al, b2, out, Nn);
}

// Round 5
// 360.950 us; speedup vs baseline: 1.9378x; 1.9378x over previous
//
#include <hip/hip_runtime.h>
#include <hip/hip_fp16.h>

typedef __attribute__((ext_vector_type(8))) short bf16x8;
typedef __attribute__((ext_vector_type(4))) float f32x4;

__device__ __forceinline__ f32x4 mfma16(bf16x8 a, bf16x8 b, f32x4 c) {
    return __builtin_amdgcn_mfma_f32_16x16x32_bf16(a, b, c, 0, 0, 0);
}

__device__ __forceinline__ unsigned short bf16_rte(float f) {
    unsigned int u = __float_as_uint(f);
    unsigned int r = (u + 0x7FFFu + ((u >> 16) & 1u)) >> 16;
    return (unsigned short)r;
}
__device__ __forceinline__ float bf16_f(unsigned short h) {
    return __uint_as_float(((unsigned int)h) << 16);
}

// split 8 fp16 values (bit-packed) into bf16 hi/lo (exact: fp16 has 11 mantissa
// bits, hi captures 8, lo captures the rest)
__device__ __forceinline__ void split8h(bf16x8 raw, bf16x8& hi, bf16x8& lo) {
#pragma unroll
    for (int j = 0; j < 8; ++j) {
        float f = __half2float(__ushort_as_half((unsigned short)raw[j]));
        unsigned short h = bf16_rte(f);
        hi[j] = (short)h;
        lo[j] = (short)bf16_rte(f - bf16_f(h));
    }
}

// ---------------- fused weight pre-conversion (all 4 matrices, 1 launch) -----
// W (K x F fp32, row-major) -> hi/lo bf16 at [col*K + k].
__global__ __launch_bounds__(256) void k_wconv_all(
    const float* __restrict__ Wl1, const float* __restrict__ Wr1,
    const float* __restrict__ Wl2, const float* __restrict__ Wr2,
    unsigned short* __restrict__ w1ah, unsigned short* __restrict__ w1al,
    unsigned short* __restrict__ w1bh, unsigned short* __restrict__ w1bl,
    unsigned short* __restrict__ w2ah, unsigned short* __restrict__ w2al,
    unsigned short* __restrict__ w2bh, unsigned short* __restrict__ w2bl) {
    int b = blockIdx.x;  // 192 blocks: 64+64+32+32
    const float* W;
    unsigned short *hi, *lo;
    int F, e;
    if (b < 64)       { W = Wl1; hi = w1ah; lo = w1al; F = 128; e = b * 256 + threadIdx.x; }
    else if (b < 128) { W = Wr1; hi = w1bh; lo = w1bl; F = 128; e = (b - 64) * 256 + threadIdx.x; }
    else if (b < 160) { W = Wl2; hi = w2ah; lo = w2al; F = 64;  e = (b - 128) * 256 + threadIdx.x; }
    else              { W = Wr2; hi = w2bh; lo = w2bl; F = 64;  e = (b - 160) * 256 + threadIdx.x; }
    if (e >= 128 * F) return;
    int col = e >> 7, k = e & 127;
    float v = W[(size_t)k * F + col];
    unsigned short h = bf16_rte(v);
    hi[e] = h;
    lo[e] = bf16_rte(v - bf16_f(h));
}

// ---------------- x fp32 -> fp16 table (row-major) ----------------
__global__ __launch_bounds__(256) void k_xconv(const float* __restrict__ x,
                                               unsigned short* __restrict__ x16,
                                               int total8) {
    int i = blockIdx.x * 256 + threadIdx.x;
    if (i >= total8) return;
    const float4* xp = (const float4*)x + (size_t)i * 2;
    float4 a = xp[0], b = xp[1];
    bf16x8 o;
    o[0] = (short)__half_as_ushort(__float2half_rn(a.x));
    o[1] = (short)__half_as_ushort(__float2half_rn(a.y));
    o[2] = (short)__half_as_ushort(__float2half_rn(a.z));
    o[3] = (short)__half_as_ushort(__float2half_rn(a.w));
    o[4] = (short)__half_as_ushort(__float2half_rn(b.x));
    o[5] = (short)__half_as_ushort(__float2half_rn(b.y));
    o[6] = (short)__half_as_ushort(__float2half_rn(b.z));
    o[7] = (short)__half_as_ushort(__float2half_rn(b.w));
    *(bf16x8*)&x16[(size_t)i * 8] = o;
}

// ---------------- bucketed CSR build, two-level (proven) ------------

#define MAXNB 1024

__global__ __launch_bounds__(256) void k_bcount(
    const int* __restrict__ dst, int* __restrict__ bcnt, int E, int chunk, int nb) {
    __shared__ int h[MAXNB];
    int t = threadIdx.x;
    for (int i = t; i < nb; i += 256) h[i] = 0;
    __syncthreads();
    int base = blockIdx.x * chunk;
    int end = min(base + chunk, E);
    for (int i = base + t; i < end; i += 256) atomicAdd(&h[dst[i] >> 7], 1);
    __syncthreads();
    for (int i = t; i < nb; i += 256)
        if (h[i]) atomicAdd(&bcnt[i], h[i]);
}

__global__ void k_bscan(const int* __restrict__ bcnt, int* __restrict__ boff,
                        int* __restrict__ bcur, int nb) {
    __shared__ int sh[1024];
    int t = threadIdx.x;
    int v = (t < nb) ? bcnt[t] : 0;
    sh[t] = v;
    __syncthreads();
    for (int off = 1; off < 1024; off <<= 1) {
        int u = (t >= off) ? sh[t - off] : 0;
        __syncthreads();
        sh[t] += u;
        __syncthreads();
    }
    if (t < nb) {
        int ex = sh[t] - v;
        boff[t] = ex;
        bcur[t] = ex;
    }
}

__global__ __launch_bounds__(256) void k_bscatter(
    const int* __restrict__ src, const int* __restrict__ dst,
    int* __restrict__ bcur, int2* __restrict__ pairs, int E, int chunk, int nb) {
    __shared__ int h[MAXNB];
    __shared__ int curs[MAXNB];
    int t = threadIdx.x;
    for (int i = t; i < nb; i += 256) h[i] = 0;
    __syncthreads();
    int base = blockIdx.x * chunk;
    int end = min(base + chunk, E);
    for (int i = base + t; i < end; i += 256) atomicAdd(&h[dst[i] >> 7], 1);
    __syncthreads();
    for (int i = t; i < nb; i += 256)
        curs[i] = h[i] ? atomicAdd(&bcur[i], h[i]) : 0;
    __syncthreads();
    for (int i = base + t; i < end; i += 256) {
        int d = dst[i];
        int p = atomicAdd(&curs[d >> 7], 1);
        pairs[p] = make_int2(d, src[i]);
    }
}

__global__ __launch_bounds__(256) void k_build(
    const int2* __restrict__ pairs, const int* __restrict__ boff,
    int* __restrict__ csr, int* __restrict__ start, int* __restrict__ deg,
    int n, int nb, int E) {
    __shared__ int scnt[128];
    __shared__ int soff[128];
    __shared__ int cur[128];
    int b = blockIdx.x;
    int t = threadIdx.x;
    int base = boff[b];
    int end = (b + 1 < nb) ? boff[b + 1] : E;
    if (t < 128) scnt[t] = 0;
    __syncthreads();
    for (int i = base + t; i < end; i += 256) {
        int2 e = pairs[i];
        atomicAdd(&scnt[e.x & 127], 1);
    }
    __syncthreads();
    if (t < 128) soff[t] = scnt[t];
    __syncthreads();
    for (int off = 1; off < 128; off <<= 1) {
        int val = 0;
        if (t < 128 && t >= off) val = soff[t - off];
        __syncthreads();
        if (t < 128) soff[t] += val;
        __syncthreads();
    }
    if (t < 128) {
        int c = scnt[t];
        int ex = soff[t] - c;
        int node = b * 128 + t;
        if (node < n) {
            start[node] = base + ex;
            deg[node] = c;
        }
        cur[t] = base + ex;
    }
    __syncthreads();
    for (int i = base + t; i < end; i += 256) {
        int2 e = pairs[i];
        int p = atomicAdd(&cur[e.x & 127], 1);
        csr[p] = e.y;
    }
}

// ---------------- dual-source fused GEMM (round-3 core, proven) -------------
// acc = X0@W0 + X1@W1 per 64-node tile, two LDS phases, 4 waves over cols.
// Both sources are fp16 row-major tables; staging uses exact split8h.

#define SR 40

template <int FOUT, bool OUT_H16>
__device__ __forceinline__ void gemm_dual_body(
    const unsigned short* __restrict__ X0h, const unsigned short* __restrict__ X1h,
    const unsigned short* __restrict__ W0H, const unsigned short* __restrict__ W0L,
    const unsigned short* __restrict__ W1H, const unsigned short* __restrict__ W1L,
    const float* __restrict__ bias, unsigned short* __restrict__ dstH,
    float* __restrict__ dstF, int n) {
    constexpr int CT = FOUT / 64;  // 16-col tiles per wave (4 waves cover FOUT)
    __shared__ unsigned short aHi[4][64 * SR], aLo[4][64 * SR];

    int t = threadIdx.x;
    int wv = t >> 6, l = t & 63, q = l >> 4, nl = l & 15;
    int wc = wv * (FOUT / 4);
    int node0 = blockIdx.x * 64;
    int sn = t >> 2, q4 = t & 3;  // staging: 4 threads per node
    int gn = min(node0 + sn, n - 1);

    // S1 row prefetch into regs (fp16)
    bf16x8 s1r[4];
    {
        const unsigned short* p = X1h + (size_t)gn * 128 + q4 * 8;
#pragma unroll
        for (int c = 0; c < 4; ++c) s1r[c] = *(const bf16x8*)(p + c * 32);
    }
    // W1 chunk-0 frag preload
    bf16x8 w1h0[CT], w1l0[CT];
#pragma unroll
    for (int uu = 0; uu < CT; ++uu) {
        int base = (wc + uu * 16 + nl) * 128 + q * 8;
        w1h0[uu] = *(const bf16x8*)&W1H[base];
        w1l0[uu] = *(const bf16x8*)&W1L[base];
    }

    // ---- phase 0: stage S0 (all of K=128), 1 barrier, 4-chunk MFMA ----
    {
        const unsigned short* p = X0h + (size_t)gn * 128 + q4 * 8;
        bf16x8 r[4];
#pragma unroll
        for (int c = 0; c < 4; ++c) r[c] = *(const bf16x8*)(p + c * 32);
        int base = sn * SR + q4 * 8;
#pragma unroll
        for (int c = 0; c < 4; ++c) {
            bf16x8 hi, lo;
            split8h(r[c], hi, lo);
            *(bf16x8*)&aHi[c][base] = hi;
            *(bf16x8*)&aLo[c][base] = lo;
        }
    }

    f32x4 acc[4][CT];
#pragma unroll
    for (int a = 0; a < 4; ++a)
#pragma unroll
        for (int b = 0; b < CT; ++b) acc[a][b] = (f32x4){0.f, 0.f, 0.f, 0.f};

    bf16x8 wh[2][CT], wl[2][CT];
#pragma unroll
    for (int uu = 0; uu < CT; ++uu) {
        int base = (wc + uu * 16 + nl) * 128 + q * 8;
        wh[0][uu] = *(const bf16x8*)&W0H[base];
        wl[0][uu] = *(const bf16x8*)&W0L[base];
    }
    __syncthreads();

#pragma unroll
    for (int c = 0; c < 4; ++c) {
        if (c < 3) {
#pragma unroll
            for (int uu = 0; uu < CT; ++uu) {
                int base = (wc + uu * 16 + nl) * 128 + (c + 1) * 32 + q * 8;
                wh[(c + 1) & 1][uu] = *(const bf16x8*)&W0H[base];
                wl[(c + 1) & 1][uu] = *(const bf16x8*)&W0L[base];
            }
        }
        bf16x8 ah[4], al[4];
#pragma unroll
        for (int tt = 0; tt < 4; ++tt) {
            int off = (tt * 16 + nl) * SR + q * 8;
            ah[tt] = *(const bf16x8*)&aHi[c][off];
            al[tt] = *(const bf16x8*)&aLo[c][off];
        }
        int cb = c & 1;
#pragma unroll
        for (int tt = 0; tt < 4; ++tt)
#pragma unroll
            for (int uu = 0; uu < CT; ++uu) {
                f32x4 a = acc[tt][uu];
                a = mfma16(al[tt], wh[cb][uu], a);
                a = mfma16(ah[tt], wl[cb][uu], a);
                a = mfma16(ah[tt], wh[cb][uu], a);
                acc[tt][uu] = a;
            }
    }
    __syncthreads();

    // ---- phase 1: stage S1 from regs ----
    {
        int base = sn * SR + q4 * 8;
#pragma unroll
        for (int c = 0; c < 4; ++c) {
            bf16x8 hi, lo;
            split8h(s1r[c], hi, lo);
            *(bf16x8*)&aHi[c][base] = hi;
            *(bf16x8*)&aLo[c][base] = lo;
        }
    }
#pragma unroll
    for (int uu = 0; uu < CT; ++uu) { wh[0][uu] = w1h0[uu]; wl[0][uu] = w1l0[uu]; }
    __syncthreads();

#pragma unroll
    for (int c = 0; c < 4; ++c) {
        if (c < 3) {
#pragma unroll
            for (int uu = 0; uu < CT; ++uu) {
                int base = (wc + uu * 16 + nl) * 128 + (c + 1) * 32 + q * 8;
                wh[(c + 1) & 1][uu] = *(const bf16x8*)&W1H[base];
                wl[(c + 1) & 1][uu] = *(const bf16x8*)&W1L[base];
            }
        }
        bf16x8 ah[4], al[4];
#pragma unroll
        for (int tt = 0; tt < 4; ++tt) {
            int off = (tt * 16 + nl) * SR + q * 8;
            ah[tt] = *(const bf16x8*)&aHi[c][off];
            al[tt] = *(const bf16x8*)&aLo[c][off];
        }
        int cb = c & 1;
#pragma unroll
        for (int tt = 0; tt < 4; ++tt)
#pragma unroll
            for (int uu = 0; uu < CT; ++uu) {
                f32x4 a = acc[tt][uu];
                a = mfma16(al[tt], wh[cb][uu], a);
                a = mfma16(ah[tt], wl[cb][uu], a);
                a = mfma16(ah[tt], wh[cb][uu], a);
                acc[tt][uu] = a;
            }
    }
    __syncthreads();

    // ---- epilogue: bias (+relu), LDS transpose, coalesced row stores ----
    if (OUT_H16) {
        unsigned short* tb = &aHi[0][0];  // 64 x 136 ushorts = 17408 B (fits)
#pragma unroll
        for (int uu = 0; uu < CT; ++uu) {
            int col = wc + uu * 16 + nl;
            float bv = bias[col];
#pragma unroll
            for (int tt = 0; tt < 4; ++tt)
#pragma unroll
                for (int r = 0; r < 4; ++r) {
                    float vv = fmaxf(acc[tt][uu][r] + bv, 0.f);
                    tb[(tt * 16 + q * 4 + r) * 136 + col] =
                        __half_as_ushort(__float2half_rn(vv));
                }
        }
        __syncthreads();
        int node = node0 + sn;
        if (node < n) {
            const unsigned short* sp = tb + sn * 136 + q4 * 32;
            unsigned short* dp = dstH + (size_t)node * 128 + q4 * 32;
#pragma unroll
            for (int i = 0; i < 4; ++i) *(bf16x8*)(dp + i * 8) = *(const bf16x8*)(sp + i * 8);
        }
    } else {
        float* tb = (float*)&aHi[0][0];  // 64 x 68 floats = 17408 B (fits)
#pragma unroll
        for (int uu = 0; uu < CT; ++uu) {
            int col = wc + uu * 16 + nl;
            float bv = bias[col];
#pragma unroll
            for (int tt = 0; tt < 4; ++tt)
#pragma unroll
                for (int r = 0; r < 4; ++r)
                    tb[(tt * 16 + q * 4 + r) * 68 + col] = acc[tt][uu][r] + bv;
        }
        __syncthreads();
        int node = node0 + sn;
        if (node < n) {
            const float* sp = tb + sn * 68 + q4 * 16;
            float* dp = dstF + (size_t)node * 64 + q4 * 16;
#pragma unroll
            for (int i = 0; i < 4; ++i) *(float4*)(dp + i * 4) = *(const float4*)(sp + i * 4);
        }
    }
}

// layer 1: h16 = relu(x@Wr1 + xm@Wl1 + b1)
__global__ __launch_bounds__(256, 2) void gemm1f(
    const unsigned short* __restrict__ X, const unsigned short* __restrict__ XM,
    const unsigned short* WrH, const unsigned short* WrL,
    const unsigned short* WlH, const unsigned short* WlL,
    const float* __restrict__ bias, unsigned short* __restrict__ h16, int n) {
    gemm_dual_body<128, true>(X, XM, WrH, WrL, WlH, WlL, bias, h16, nullptr, n);
}

// layer 2: out = h@Wr2 + hm@Wl2 + b2
__global__ __launch_bounds__(256, 2) void gemm2f(
    const unsigned short* __restrict__ H, const unsigned short* __restrict__ HM,
    const unsigned short* WrH, const unsigned short* WrL,
    const unsigned short* WlH, const unsigned short* WlL,
    const float* __restrict__ bias, float* __restrict__ out, int n) {
    gemm_dual_body<64, false>(H, HM, WrH, WrL, WlH, WlL, bias, nullptr, out, n);
}

// ---------------- mean aggregation (round-3 shape + csr pipelining) ---------
// 2 nodes/wave, 32 lanes x 8 B per row. Index loads for group j+4 issue BEFORE
// group j's table gathers so csr latency hides under gather latency.
__global__ void aggF(const unsigned short* __restrict__ tab, const int* __restrict__ csr,
                     const int* __restrict__ start, const int* __restrict__ deg,
                     unsigned short* __restrict__ outm, int n) {
    int gid = blockIdx.x * blockDim.x + threadIdx.x;
    int wave = gid >> 6, lane = gid & 63;
    int half = lane >> 5, fl = lane & 31;
    int node = wave * 2 + half;
    if (node >= n) return;
    int s = start[node], d = deg[node];
    const float2* u2 = (const float2*)tab;  // 4 halfs per float2
    float4 A = {0.f, 0.f, 0.f, 0.f}, B = {0.f, 0.f, 0.f, 0.f};
    int j = 0;
    int i0 = 0, i1 = 0, i2 = 0, i3 = 0;
    if (j + 4 <= d) { i0 = csr[s]; i1 = csr[s + 1]; i2 = csr[s + 2]; i3 = csr[s + 3]; }
    for (; j + 8 <= d; j += 4) {
        int n0 = csr[s + j + 4], n1 = csr[s + j + 5];
        int n2 = csr[s + j + 6], n3 = csr[s + j + 7];
        float2 r0 = u2[(size_t)i0 * 32 + fl];
        float2 r1 = u2[(size_t)i1 * 32 + fl];
        float2 r2 = u2[(size_t)i2 * 32 + fl];
        float2 r3 = u2[(size_t)i3 * 32 + fl];
        float2 a0 = __half22float2(*(const __half2*)&r0.x), b0 = __half22float2(*(const __half2*)&r0.y);
        float2 a1 = __half22float2(*(const __half2*)&r1.x), b1 = __half22float2(*(const __half2*)&r1.y);
        float2 a2 = __half22float2(*(const __half2*)&r2.x), b2 = __half22float2(*(const __half2*)&r2.y);
        float2 a3 = __half22float2(*(const __half2*)&r3.x), b3 = __half22float2(*(const __half2*)&r3.y);
        A.x += a0.x + a1.x; A.y += a0.y + a1.y;
        A.z += b0.x + b1.x; A.w += b0.y + b1.y;
        B.x += a2.x + a3.x; B.y += a2.y + a3.y;
        B.z += b2.x + b3.x; B.w += b2.y + b3.y;
        i0 = n0; i1 = n1; i2 = n2; i3 = n3;
    }
    if (j + 4 <= d) {
        float2 r0 = u2[(size_t)i0 * 32 + fl];
        float2 r1 = u2[(size_t)i1 * 32 + fl];
        float2 r2 = u2[(size_t)i2 * 32 + fl];
        float2 r3 = u2[(size_t)i3 * 32 + fl];
        float2 a0 = __half22float2(*(const __half2*)&r0.x), b0 = __half22float2(*(const __half2*)&r0.y);
        float2 a1 = __half22float2(*(const __half2*)&r1.x), b1 = __half22float2(*(const __half2*)&r1.y);
        float2 a2 = __half22float2(*(const __half2*)&r2.x), b2 = __half22float2(*(const __half2*)&r2.y);
        float2 a3 = __half22float2(*(const __half2*)&r3.x), b3 = __half22float2(*(const __half2*)&r3.y);
        A.x += a0.x + a1.x; A.y += a0.y + a1.y;
        A.z += b0.x + b1.x; A.w += b0.y + b1.y;
        B.x += a2.x + a3.x; B.y += a2.y + a3.y;
        B.z += b2.x + b3.x; B.w += b2.y + b3.y;
        j += 4;
    }
    for (; j < d; ++j) {
        float2 r0 = u2[(size_t)csr[s + j] * 32 + fl];
        float2 a0 = __half22float2(*(const __half2*)&r0.x), b0 = __half22float2(*(const __half2*)&r0.y);
        A.x += a0.x; A.y += a0.y; A.z += b0.x; A.w += b0.y;
    }
    float inv = 1.0f / (float)max(d, 1);
    float mx = (A.x + B.x) * inv, my = (A.y + B.y) * inv;
    float mz = (A.z + B.z) * inv, mw = (A.w + B.w) * inv;
    __half2 h01 = __floats2half2_rn(mx, my);
    __half2 h23 = __floats2half2_rn(mz, mw);
    uint2 w;
    w.x = *(unsigned int*)&h01;
    w.y = *(unsigned int*)&h23;
    *(uint2*)&outm[(size_t)node * 128 + fl * 4] = w;
}

// ---------------- launch ----------------

extern "C" void kernel_launch(void* const* d_in, const int* in_sizes, int n_in,
                              void* d_out, int out_size, void* d_ws, size_t ws_size,
                              hipStream_t stream) {
    const float* x   = (const float*)d_in[0];
    const int*   ei  = (const int*)d_in[1];
    const float* Wl1 = (const float*)d_in[2];
    const float* Wr1 = (const float*)d_in[3];
    const float* b1  = (const float*)d_in[4];
    const float* Wl2 = (const float*)d_in[5];
    const float* Wr2 = (const float*)d_in[6];
    const float* b2  = (const float*)d_in[7];
    float* out = (float*)d_out;

    int Nn = in_sizes[0] / 128;
    int E  = in_sizes[1] / 2;
    const int* src = ei;
    const int* dst = ei + E;
    int nb = (Nn + 127) / 128;  // 782 <= MAXNB

    char* ws = (char*)d_ws;
    auto alloc = [&](size_t bytes) -> char* {
        char* pp = ws;
        ws += (bytes + 255) / 256 * 256;
        return pp;
    };
    int* bcnt   = (int*)alloc((size_t)nb * 4);
    int* boff   = (int*)alloc((size_t)nb * 4);
    int* bcur   = (int*)alloc((size_t)nb * 4);
    int* start  = (int*)alloc((size_t)Nn * 4);
    int* deg    = (int*)alloc((size_t)Nn * 4);
    int* csr    = (int*)alloc((size_t)E * 4);
    unsigned short* x16  = (unsigned short*)alloc((size_t)Nn * 128 * 2);
    unsigned short* xm16 = (unsigned short*)alloc((size_t)Nn * 128 * 2);
    unsigned short* h16  = (unsigned short*)alloc((size_t)Nn * 128 * 2);
    unsigned short* hm16 = (unsigned short*)alloc((size_t)Nn * 128 * 2);
    unsigned short* w1ah = (unsigned short*)alloc(128 * 128 * 2);
    unsigned short* w1al = (unsigned short*)alloc(128 * 128 * 2);
    unsigned short* w1bh = (unsigned short*)alloc(128 * 128 * 2);
    unsigned short* w1bl = (unsigned short*)alloc(128 * 128 * 2);
    unsigned short* w2ah = (unsigned short*)alloc(64 * 128 * 2);
    unsigned short* w2al = (unsigned short*)alloc(64 * 128 * 2);
    unsigned short* w2bh = (unsigned short*)alloc(64 * 128 * 2);
    unsigned short* w2bl = (unsigned short*)alloc(64 * 128 * 2);
    // pairs (12.8 MB) aliases hm16 (25.6 MB): consumed by k_build before
    // aggF(h16) writes hm16
    int2* pairs = (int2*)hm16;

    hipMemsetAsync(bcnt, 0, (size_t)nb * 4, stream);

    k_wconv_all<<<192, 256, 0, stream>>>(Wl1, Wr1, Wl2, Wr2,
                                         w1ah, w1al, w1bh, w1bl,
                                         w2ah, w2al, w2bh, w2bl);
    k_xconv<<<(Nn * 16 + 255) / 256, 256, 0, stream>>>(x, x16, Nn * 16);

    int chunk = (E + 255) / 256;
    k_bcount<<<256, 256, 0, stream>>>(dst, bcnt, E, chunk, nb);
    k_bscan<<<1, 1024, 0, stream>>>(bcnt, boff, bcur, nb);
    k_bscatter<<<256, 256, 0, stream>>>(src, dst, bcur, pairs, E, chunk, nb);
    k_build<<<nb, 256, 0, stream>>>(pairs, boff, csr, start, deg, Nn, nb, E);

    int gb = (Nn + 63) / 64;
    // layer 1: xm = mean-agg(x); h = relu(xm@Wl1 + x@Wr1 + b1)   [linearity]
    aggF<<<(Nn + 7) / 8, 256, 0, stream>>>(x16, csr, start, deg, xm16, Nn);
    gemm1f<<<gb, 256, 0, stream>>>(x16, xm16, w1bh, w1bl, w1ah, w1al, b1, h16, Nn);
    // layer 2: hm = mean-agg(h); out = hm@Wl2 + h@Wr2 + b2       [linearity]
    aggF<<<(Nn + 7) / 8, 256, 0, stream>>>(h16, csr, start, deg, hm16, Nn);
    gemm2f<<<gb, 256, 0, stream>>>(h16, hm16, w2bh, w2bl, w2ah, w2al, b2, out, Nn);
}